// Round 2
// baseline (32577.136 us; speedup 1.0000x reference)
//
#include <hip/hip_runtime.h>

// 2-layer LSTM (H=50, B=4096, T=512, D_in=1) + FC(50->1), fused, MFMA-based.
//
// Per block: 16 batches, all 512 timesteps. Grid = 256 blocks (1/CU), 512 thr.
// Gates G[208x16] = W[208xK] * Hcat[Kx16] via v_mfma_f32_16x16x32_bf16 with
// hi/lo bf16 split (3 products: Ah*Bh + Ah*Bl + Al*Bh ~ fp32 accuracy, ~2^-16).
// Layer0: K=64 (h1 padded 50->64, ksteps 0..1). Layer1: K=128 ([h1|pad|h2|pad],
// ksteps 0..3). h-state stored in LDS pre-permuted into exact B-fragment layout
// (B[k][n]: lane = ((k>>3)&3)*16 + n, j = k&7) so the hot read is one
// ds_read_b128 per kstep at lane*16 -- conflict-free.
// Weights held as A-fragments in VGPRs (wave w owns M-tiles {w, 8+w if w<5}).
// C/D layout: col = lane&15 (batch), row = (lane>>4)*4 + reg   [m89-verified].

#define TT 512
#define HH 50
#define NG 200
#define BT 16          // batch tile per block
#define NT 13          // 16-row M tiles (208 rows, 200 valid)
#define GS 17          // G row stride in fp32 (pad: 2-way max conflict = free)

typedef short short8 __attribute__((ext_vector_type(8)));
typedef float floatx4 __attribute__((ext_vector_type(4)));

__device__ __forceinline__ float fast_sig(float x) {
    float e = __builtin_amdgcn_exp2f(x * -1.44269504f);   // exp(-x)
    return __builtin_amdgcn_rcpf(1.0f + e);
}
__device__ __forceinline__ float fast_tanh(float x) {
    float e = __builtin_amdgcn_exp2f(x * -2.88539008f);   // exp(-2x)
    return __builtin_amdgcn_rcpf(1.0f + e) * 2.0f - 1.0f;
}
__device__ __forceinline__ void split_bf16(float x, short& hi, short& lo) {
    unsigned u = __float_as_uint(x);
    hi = (short)(u >> 16);                      // truncate to bf16
    float xh = __uint_as_float(u & 0xffff0000u);
    lo = (short)(__float_as_uint(x - xh) >> 16);  // residual, truncated
}

__global__ __launch_bounds__(512, 2) void lstm_mfma(
    const float* __restrict__ x,
    const float* __restrict__ W_ih0, const float* __restrict__ W_hh0,
    const float* __restrict__ b_ih0, const float* __restrict__ b_hh0,
    const float* __restrict__ W_ih1, const float* __restrict__ W_hh1,
    const float* __restrict__ b_ih1, const float* __restrict__ b_hh1,
    const float* __restrict__ W_fc,  const float* __restrict__ b_fc,
    float* __restrict__ out)
{
    __shared__ __align__(16) short Hhi[4 * 64 * 8];   // [ks][lane][j] bf16 hi
    __shared__ __align__(16) short Hlo[4 * 64 * 8];   // [ks][lane][j] bf16 lo
    __shared__ float G[NT * 16 * GS];                 // 208 x 17 gate buffer
    __shared__ float xs[TT * BT];                     // [t][n]
    __shared__ float h2f[BT * HH];                    // final h2 (fp32) for FC

    const int tid = threadIdx.x;
    const int ln  = tid & 63;
    const int wv  = tid >> 6;          // wave 0..7
    const int b0  = blockIdx.x * BT;

    // ---------------- one-time init ----------------
    // x -> LDS, transposed to [t][n] so per-step reads are conflict-free
    for (int i = tid; i < BT * TT; i += 512) {
        int b = i >> 9, t = i & (TT - 1);
        xs[t * BT + b] = x[(size_t)(b0 + b) * TT + t];
    }
    for (int i = tid; i < 4 * 64 * 8; i += 512) { Hhi[i] = 0; Hlo[i] = 0; }

    // A-fragment construction (weights -> VGPRs, hi/lo bf16)
    const int m = ln & 15, q = ln >> 4;
    const int ntile = (wv < 5) ? 2 : 1;
    int tiles[2]; tiles[0] = wv; tiles[1] = 8 + wv;

    short8 a0h[2][2], a0l[2][2];       // layer0: [tile][kstep]
    short8 a1h[2][4], a1l[2][4];       // layer1: [tile][kstep]
    float  b0v[2][4], w0v[2][4], b1v[2][4];   // per-(tile,reg) row constants

    for (int ti = 0; ti < 2; ++ti) {
        const int row = tiles[ti] * 16 + m;
        const bool tok = (ti < ntile) && (row < NG);
        for (int ks = 0; ks < 2; ++ks) {
            short8 h8, l8;
            for (int j = 0; j < 8; ++j) {
                int k = ks * 32 + q * 8 + j;
                float w = (tok && k < HH) ? W_hh0[row * HH + k] : 0.f;
                short hi, lo; split_bf16(w, hi, lo);
                h8[j] = hi; l8[j] = lo;
            }
            a0h[ti][ks] = h8; a0l[ti][ks] = l8;
        }
        for (int ks = 0; ks < 4; ++ks) {
            short8 h8, l8;
            for (int j = 0; j < 8; ++j) {
                int k = ks * 32 + q * 8 + j;
                float w = 0.f;
                if (tok) {
                    if (k < HH)                       w = W_ih1[row * HH + k];
                    else if (k >= 64 && k < 64 + HH)  w = W_hh1[row * HH + (k - 64)];
                }
                short hi, lo; split_bf16(w, hi, lo);
                h8[j] = hi; l8[j] = lo;
            }
            a1h[ti][ks] = h8; a1l[ti][ks] = l8;
        }
        for (int r = 0; r < 4; ++r) {
            int rr = tiles[ti] * 16 + q * 4 + r;
            bool ok = (ti < ntile) && (rr < NG);
            b0v[ti][r] = ok ? (b_ih0[rr] + b_hh0[rr]) : 0.f;
            w0v[ti][r] = ok ? W_ih0[rr] : 0.f;
            b1v[ti][r] = ok ? (b_ih1[rr] + b_hh1[rr]) : 0.f;
        }
    }

    // update-phase mapping: thread -> (batch n, unit pair {uu, uu+32})
    const int n  = tid & 15;
    const int uu = tid >> 4;           // 0..31
    float c1[2] = {0.f, 0.f};
    float c2[2] = {0.f, 0.f};

    __syncthreads();

    // ---------------- time loop ----------------
    for (int t = 0; t < TT; ++t) {
        // ---- layer 0: G = W0cat * Hcat(ksteps 0..1) ----
        {
            floatx4 acc[2];
            acc[0] = (floatx4){0.f, 0.f, 0.f, 0.f};
            acc[1] = (floatx4){0.f, 0.f, 0.f, 0.f};
            for (int ks = 0; ks < 2; ++ks) {
                short8 bh = *(const short8*)&Hhi[(ks * 64 + ln) * 8];
                short8 bl = *(const short8*)&Hlo[(ks * 64 + ln) * 8];
                for (int ti = 0; ti < ntile; ++ti) {
                    acc[ti] = __builtin_amdgcn_mfma_f32_16x16x32_bf16(a0h[ti][ks], bh, acc[ti], 0, 0, 0);
                    acc[ti] = __builtin_amdgcn_mfma_f32_16x16x32_bf16(a0h[ti][ks], bl, acc[ti], 0, 0, 0);
                    acc[ti] = __builtin_amdgcn_mfma_f32_16x16x32_bf16(a0l[ti][ks], bh, acc[ti], 0, 0, 0);
                }
            }
            float xval = xs[t * BT + m];
            for (int ti = 0; ti < ntile; ++ti) {
                int rbase = tiles[ti] * 16 + q * 4;
                for (int r = 0; r < 4; ++r)
                    G[(rbase + r) * GS + m] = acc[ti][r] + b0v[ti][r] + w0v[ti][r] * xval;
            }
        }
        __syncthreads();   // G0 ready; all h1-old B-frag reads done

        // ---- update 0: c1/h1; write h1 (bf16 hi/lo) into B-frag slots k=u ----
        for (int kk = 0; kk < 2; ++kk) {
            int u = uu + 32 * kk;
            if (u < HH) {
                float gi = G[u * GS + n];
                float gf = G[(u + HH) * GS + n];
                float gg = G[(u + 2 * HH) * GS + n];
                float go = G[(u + 3 * HH) * GS + n];
                float c = fast_sig(gf) * c1[kk] + fast_sig(gi) * fast_tanh(gg);
                c1[kk] = c;
                float h = fast_sig(go) * fast_tanh(c);
                short hi, lo; split_bf16(h, hi, lo);
                int idx = (((u >> 5) * 64) + (((u >> 3) & 3) * 16) + n) * 8 + (u & 7);
                Hhi[idx] = hi; Hlo[idx] = lo;
            }
        }
        __syncthreads();   // h1-new visible; G0 reads done

        // ---- layer 1: G = W1cat * Hcat(ksteps 0..3) ----
        {
            floatx4 acc[2];
            acc[0] = (floatx4){0.f, 0.f, 0.f, 0.f};
            acc[1] = (floatx4){0.f, 0.f, 0.f, 0.f};
            for (int ks = 0; ks < 4; ++ks) {
                short8 bh = *(const short8*)&Hhi[(ks * 64 + ln) * 8];
                short8 bl = *(const short8*)&Hlo[(ks * 64 + ln) * 8];
                for (int ti = 0; ti < ntile; ++ti) {
                    acc[ti] = __builtin_amdgcn_mfma_f32_16x16x32_bf16(a1h[ti][ks], bh, acc[ti], 0, 0, 0);
                    acc[ti] = __builtin_amdgcn_mfma_f32_16x16x32_bf16(a1h[ti][ks], bl, acc[ti], 0, 0, 0);
                    acc[ti] = __builtin_amdgcn_mfma_f32_16x16x32_bf16(a1l[ti][ks], bh, acc[ti], 0, 0, 0);
                }
            }
            for (int ti = 0; ti < ntile; ++ti) {
                int rbase = tiles[ti] * 16 + q * 4;
                for (int r = 0; r < 4; ++r)
                    G[(rbase + r) * GS + m] = acc[ti][r] + b1v[ti][r];
            }
        }
        __syncthreads();   // G1 ready; all h2-old B-frag reads done

        // ---- update 1: c2/h2; write h2 into B-frag slots k=64+u ----
        for (int kk = 0; kk < 2; ++kk) {
            int u = uu + 32 * kk;
            if (u < HH) {
                float gi = G[u * GS + n];
                float gf = G[(u + HH) * GS + n];
                float gg = G[(u + 2 * HH) * GS + n];
                float go = G[(u + 3 * HH) * GS + n];
                float c = fast_sig(gf) * c2[kk] + fast_sig(gi) * fast_tanh(gg);
                c2[kk] = c;
                float h = fast_sig(go) * fast_tanh(c);
                short hi, lo; split_bf16(h, hi, lo);
                int k = 64 + u;
                int idx = (((k >> 5) * 64) + (((k >> 3) & 3) * 16) + n) * 8 + (k & 7);
                Hhi[idx] = hi; Hlo[idx] = lo;
                if (t == TT - 1) h2f[n * HH + u] = h;
            }
        }
        __syncthreads();   // h2-new visible; next step safe
    }

    // ---------------- FC epilogue ----------------
    if (tid < BT) {
        float acc = b_fc[0];
        for (int u = 0; u < HH; ++u)
            acc = fmaf(h2f[tid * HH + u], W_fc[u], acc);
        out[b0 + tid] = acc;
    }
}

extern "C" void kernel_launch(void* const* d_in, const int* in_sizes, int n_in,
                              void* d_out, int out_size, void* d_ws, size_t ws_size,
                              hipStream_t stream) {
    const float* x     = (const float*)d_in[0];
    const float* W_ih0 = (const float*)d_in[1];
    const float* W_hh0 = (const float*)d_in[2];
    const float* b_ih0 = (const float*)d_in[3];
    const float* b_hh0 = (const float*)d_in[4];
    const float* W_ih1 = (const float*)d_in[5];
    const float* W_hh1 = (const float*)d_in[6];
    const float* b_ih1 = (const float*)d_in[7];
    const float* b_hh1 = (const float*)d_in[8];
    const float* W_fc  = (const float*)d_in[9];
    const float* b_fc  = (const float*)d_in[10];
    float* out = (float*)d_out;

    dim3 grid(4096 / BT);   // 256 blocks = 1 per CU
    dim3 block(512);        // 8 waves
    lstm_mfma<<<grid, block, 0, stream>>>(x, W_ih0, W_hh0, b_ih0, b_hh0,
                                          W_ih1, W_hh1, b_ih1, b_hh1,
                                          W_fc, b_fc, out);
}

// Round 3
// 799.834 us; speedup vs baseline: 40.7298x; 40.7298x over previous
//
#include <hip/hip_runtime.h>

// 2-layer LSTM (H=50, B=4096, T=512, D_in=1) + FC(50->1), fused, MFMA.
//
// Per block: 16 batches, all 512 steps. 256 blocks (1/CU) x 512 threads (8 waves).
// Gates G[200x16] = W[200xK] * Hcat[Kx16] via v_mfma_f32_16x16x32_bf16, hi/lo
// bf16 split, 3 products (Ah*Bh + Ah*Bl + Al*Bh ~ fp32 accuracy).
// Hcat B-fragment LDS layout (verified passing in round 2):
//   k -> ks = k>>5, lane = ((k>>3)&3)*16 + col, j = k&7 ; read = b128 @ lane*16.
//   ks 0..1 = h1 (k 0..49), ks 2..3 = h2 (k 64..113).
// A-fragments in registers: wave wv owns tiles {wv, 8+wv}; tile 2 rows >= 200
// are zero-weight dummies (MFMA runs uniformly; only the G-store is masked).
// ALL fragment loops have compile-time bounds -> no scratch spills (the round-2
// failure: runtime `ntile` bound -> runtime array index -> 1.3 GB spill traffic).
// G layout: [col][row], row-stride RS=212 -> b128 stores (conflict-even),
// float2 update reads (2-way max = free).
// Pipelined: phase1 = [B_{t-1} + A_t] (shared B-frag reads), phase2 =
// [U1_{t-1} + U0_t] -> 2 barriers/step.

#define TT 512
#define HH 50
#define NG 200
#define BT 16
#define RS 212

typedef short short8 __attribute__((ext_vector_type(8)));
typedef float floatx4 __attribute__((ext_vector_type(4)));

static __device__ __forceinline__ float fast_sig(float x) {
    float e = __builtin_amdgcn_exp2f(x * -1.44269504f);   // exp(-x)
    return __builtin_amdgcn_rcpf(1.0f + e);
}
static __device__ __forceinline__ float fast_tanh(float x) {
    float e = __builtin_amdgcn_exp2f(x * -2.88539008f);   // exp(-2x)
    return __builtin_amdgcn_rcpf(1.0f + e) * 2.0f - 1.0f;
}
static __device__ __forceinline__ void split_bf16(float x, short& hi, short& lo) {
    unsigned u = __float_as_uint(x);
    hi = (short)(u >> 16);
    float xh = __uint_as_float(u & 0xffff0000u);
    lo = (short)(__float_as_uint(x - xh) >> 16);
}

__global__ __launch_bounds__(512, 2) void lstm_mfma(
    const float* __restrict__ x,
    const float* __restrict__ W_ih0, const float* __restrict__ W_hh0,
    const float* __restrict__ b_ih0, const float* __restrict__ b_hh0,
    const float* __restrict__ W_ih1, const float* __restrict__ W_hh1,
    const float* __restrict__ b_ih1, const float* __restrict__ b_hh1,
    const float* __restrict__ W_fc,  const float* __restrict__ b_fc,
    float* __restrict__ out)
{
    __shared__ __align__(16) short Hhi[4 * 64 * 8];
    __shared__ __align__(16) short Hlo[4 * 64 * 8];
    __shared__ __align__(16) float G0[BT * RS];
    __shared__ __align__(16) float G1[BT * RS];
    __shared__ float xs[TT * BT];
    __shared__ float h2f[BT * HH];

    const int tid = threadIdx.x;
    const int ln  = tid & 63;
    const int wv  = tid >> 6;
    const int m   = ln & 15;      // A row-in-tile / C col (batch)
    const int q   = ln >> 4;      // A k-group / C row-group
    const int b0g = blockIdx.x * BT;

    // ---------------- one-time init ----------------
    for (int i = tid; i < BT * TT; i += 512) {
        int b = i & 15, t = i >> 4;
        xs[t * BT + b] = x[(size_t)(b0g + b) * TT + t];
    }
    for (int i = tid; i < 4 * 64 * 8; i += 512) { Hhi[i] = 0; Hlo[i] = 0; }

    // ---- A-fragments: COMPILE-TIME indexed only ----
    short8 a0h[2][2], a0l[2][2];
    short8 a1h[2][4], a1l[2][4];
    float  bw0[2][4], bb0[2][4], bb1[2][4];

#pragma unroll
    for (int ti = 0; ti < 2; ++ti) {
        const int tile = (ti == 0) ? wv : (8 + wv);
        const int row  = tile * 16 + m;
        const bool rok = (row < NG);
#pragma unroll
        for (int ks = 0; ks < 2; ++ks) {
            short8 h8, l8;
#pragma unroll
            for (int j = 0; j < 8; ++j) {
                int k = ks * 32 + q * 8 + j;
                float w = (rok && k < HH) ? W_hh0[row * HH + k] : 0.f;
                short hi, lo; split_bf16(w, hi, lo);
                h8[j] = hi; l8[j] = lo;
            }
            a0h[ti][ks] = h8; a0l[ti][ks] = l8;
        }
#pragma unroll
        for (int ks = 0; ks < 4; ++ks) {
            short8 h8, l8;
#pragma unroll
            for (int j = 0; j < 8; ++j) {
                int k = ks * 32 + q * 8 + j;
                float w = 0.f;
                if (rok) {
                    if (k < HH)                      w = W_ih1[row * HH + k];
                    else if (k >= 64 && k < 64 + HH) w = W_hh1[row * HH + (k - 64)];
                }
                short hi, lo; split_bf16(w, hi, lo);
                h8[j] = hi; l8[j] = lo;
            }
            a1h[ti][ks] = h8; a1l[ti][ks] = l8;
        }
#pragma unroll
        for (int r = 0; r < 4; ++r) {
            int rr = tile * 16 + q * 4 + r;
            bool ok = (rr < NG);
            bw0[ti][r] = ok ? W_ih0[rr] : 0.f;
            bb0[ti][r] = ok ? (b_ih0[rr] + b_hh0[rr]) : 0.f;
            bb1[ti][r] = ok ? (b_ih1[rr] + b_hh1[rr]) : 0.f;
        }
    }

    // update mapping: batch n, unit pair {u0, u0+1}
    const int n  = tid & 15;
    const int uu = tid >> 4;          // 0..31; active if uu < 25
    const int u0 = 2 * uu;
    const bool uact = (uu < 25);
    // h-frag store index for k=u0 (j = u0&7 is even -> b32-packable)
    const int sidx = ((u0 >> 5) * 64 + ((u0 >> 3) & 3) * 16 + n) * 8 + (u0 & 7);
    float c1a = 0.f, c1b = 0.f, c2a = 0.f, c2b = 0.f;

    __syncthreads();

    // ---------------- pipelined time loop ----------------
    for (int tt = 0; tt <= TT; ++tt) {
        // ===== phase 1: matvecs  [A_tt if tt<TT]  [B_{tt-1} if tt>0] =====
        {
            short8 bh[4], bl[4];
#pragma unroll
            for (int ks = 0; ks < 4; ++ks) {
                bh[ks] = *(const short8*)&Hhi[(ks * 64 + ln) * 8];
                bl[ks] = *(const short8*)&Hlo[(ks * 64 + ln) * 8];
            }
            if (tt < TT) {                       // layer 0 -> G0
                floatx4 acc[2];
                acc[0] = (floatx4){0.f, 0.f, 0.f, 0.f};
                acc[1] = (floatx4){0.f, 0.f, 0.f, 0.f};
#pragma unroll
                for (int ks = 0; ks < 2; ++ks) {
#pragma unroll
                    for (int ti = 0; ti < 2; ++ti) {
                        acc[ti] = __builtin_amdgcn_mfma_f32_16x16x32_bf16(a0h[ti][ks], bh[ks], acc[ti], 0, 0, 0);
                        acc[ti] = __builtin_amdgcn_mfma_f32_16x16x32_bf16(a0h[ti][ks], bl[ks], acc[ti], 0, 0, 0);
                        acc[ti] = __builtin_amdgcn_mfma_f32_16x16x32_bf16(a0l[ti][ks], bh[ks], acc[ti], 0, 0, 0);
                    }
                }
                float xv = xs[tt * BT + m];
#pragma unroll
                for (int ti = 0; ti < 2; ++ti) {
                    if (ti == 0 || wv < 5) {
                        const int tile = (ti == 0) ? wv : (8 + wv);
                        floatx4 st;
#pragma unroll
                        for (int r = 0; r < 4; ++r)
                            st[r] = acc[ti][r] + bb0[ti][r] + bw0[ti][r] * xv;
                        *(floatx4*)&G0[m * RS + tile * 16 + q * 4] = st;
                    }
                }
            }
            if (tt > 0) {                        // layer 1 -> G1
                floatx4 acc[2];
                acc[0] = (floatx4){0.f, 0.f, 0.f, 0.f};
                acc[1] = (floatx4){0.f, 0.f, 0.f, 0.f};
#pragma unroll
                for (int ks = 0; ks < 4; ++ks) {
#pragma unroll
                    for (int ti = 0; ti < 2; ++ti) {
                        acc[ti] = __builtin_amdgcn_mfma_f32_16x16x32_bf16(a1h[ti][ks], bh[ks], acc[ti], 0, 0, 0);
                        acc[ti] = __builtin_amdgcn_mfma_f32_16x16x32_bf16(a1h[ti][ks], bl[ks], acc[ti], 0, 0, 0);
                        acc[ti] = __builtin_amdgcn_mfma_f32_16x16x32_bf16(a1l[ti][ks], bh[ks], acc[ti], 0, 0, 0);
                    }
                }
#pragma unroll
                for (int ti = 0; ti < 2; ++ti) {
                    if (ti == 0 || wv < 5) {
                        const int tile = (ti == 0) ? wv : (8 + wv);
                        floatx4 st;
#pragma unroll
                        for (int r = 0; r < 4; ++r)
                            st[r] = acc[ti][r] + bb1[ti][r];
                        *(floatx4*)&G1[m * RS + tile * 16 + q * 4] = st;
                    }
                }
            }
        }
        __syncthreads();

        // ===== phase 2: updates  [U0_tt if tt<TT]  [U1_{tt-1} if tt>0] =====
        if (uact) {
            if (tt < TT) {                       // layer-0 cell update
                float2 gi = *(const float2*)&G0[n * RS + u0];
                float2 gf = *(const float2*)&G0[n * RS + u0 + 50];
                float2 gg = *(const float2*)&G0[n * RS + u0 + 100];
                float2 go = *(const float2*)&G0[n * RS + u0 + 150];
                c1a = fast_sig(gf.x) * c1a + fast_sig(gi.x) * fast_tanh(gg.x);
                c1b = fast_sig(gf.y) * c1b + fast_sig(gi.y) * fast_tanh(gg.y);
                float ha = fast_sig(go.x) * fast_tanh(c1a);
                float hb = fast_sig(go.y) * fast_tanh(c1b);
                short hia, loa, hib, lob;
                split_bf16(ha, hia, loa); split_bf16(hb, hib, lob);
                *(unsigned*)&Hhi[sidx] = (unsigned short)hia | ((unsigned)(unsigned short)hib << 16);
                *(unsigned*)&Hlo[sidx] = (unsigned short)loa | ((unsigned)(unsigned short)lob << 16);
            }
            if (tt > 0) {                        // layer-1 cell update
                float2 gi = *(const float2*)&G1[n * RS + u0];
                float2 gf = *(const float2*)&G1[n * RS + u0 + 50];
                float2 gg = *(const float2*)&G1[n * RS + u0 + 100];
                float2 go = *(const float2*)&G1[n * RS + u0 + 150];
                c2a = fast_sig(gf.x) * c2a + fast_sig(gi.x) * fast_tanh(gg.x);
                c2b = fast_sig(gf.y) * c2b + fast_sig(gi.y) * fast_tanh(gg.y);
                float ha = fast_sig(go.x) * fast_tanh(c2a);
                float hb = fast_sig(go.y) * fast_tanh(c2b);
                short hia, loa, hib, lob;
                split_bf16(ha, hia, loa); split_bf16(hb, hib, lob);
                *(unsigned*)&Hhi[sidx + 1024] = (unsigned short)hia | ((unsigned)(unsigned short)hib << 16);
                *(unsigned*)&Hlo[sidx + 1024] = (unsigned short)loa | ((unsigned)(unsigned short)lob << 16);
                if (tt == TT) { h2f[n * HH + u0] = ha; h2f[n * HH + u0 + 1] = hb; }
            }
        }
        __syncthreads();
    }

    // ---------------- FC epilogue ----------------
    if (tid < BT) {
        float a = b_fc[0];
        for (int u = 0; u < HH; ++u)
            a = fmaf(h2f[tid * HH + u], W_fc[u], a);
        out[b0g + tid] = a;
    }
}

extern "C" void kernel_launch(void* const* d_in, const int* in_sizes, int n_in,
                              void* d_out, int out_size, void* d_ws, size_t ws_size,
                              hipStream_t stream) {
    const float* x     = (const float*)d_in[0];
    const float* W_ih0 = (const float*)d_in[1];
    const float* W_hh0 = (const float*)d_in[2];
    const float* b_ih0 = (const float*)d_in[3];
    const float* b_hh0 = (const float*)d_in[4];
    const float* W_ih1 = (const float*)d_in[5];
    const float* W_hh1 = (const float*)d_in[6];
    const float* b_ih1 = (const float*)d_in[7];
    const float* b_hh1 = (const float*)d_in[8];
    const float* W_fc  = (const float*)d_in[9];
    const float* b_fc  = (const float*)d_in[10];
    float* out = (float*)d_out;

    dim3 grid(4096 / BT);   // 256 blocks = 1/CU
    dim3 block(512);        // 8 waves
    lstm_mfma<<<grid, block, 0, stream>>>(x, W_ih0, W_hh0, b_ih0, b_hh0,
                                          W_ih1, W_hh1, b_ih1, b_hh1,
                                          W_fc, b_fc, out);
}

// Round 4
// 652.167 us; speedup vs baseline: 49.9521x; 1.2264x over previous
//
#include <hip/hip_runtime.h>

// 2-layer LSTM (H=50, B=4096, T=512, D_in=1) + FC(50->1), fused MFMA, round 4.
//
// 256 blocks (1/CU) x 512 threads (8 waves), 16 batches/block, all 512 steps.
// v_mfma_f32_16x16x32_bf16, hi/lo bf16 split, 3 products (~fp32 accuracy).
//
// KEY CHANGE vs round 3: gate-interleaved row permutation. Packed gate-row
// pr = 4*u + g (unit u, gate g in {i,f,g,o}). A-fragments are built from
// W[g*50+u], so MFMA C-layout (col=lane&15=batch, row=(lane>>4)*4+reg) puts
// ALL FOUR GATES of unit (4*tile+q) for batch m into lane (q,m)'s 4 acc regs.
// -> cell update is computed IN-REGISTER by the producing lane. The G LDS
// round-trip (26 b128 stores + 64 b64 reads + a barrier phase per iter in r3)
// is eliminated. h goes straight to the B-fragment arrays as 2-byte stores.
//
// Double-buffered H-fragments (parity tt&1) remove the WAR hazard ->
// ONE barrier per iteration (r3 had 2).
//
// Pipelining (as r3): iter tt computes layer0(t=tt) and layer1(t=tt-1) from
// one Hcat snapshot [h1(tt-1) | h2(tt-2)] read once per wave (8 x b128).
// B-frag layout (r2/r3-validated): k -> ks=k>>5, lane=((k>>3)&3)*16+n, j=k&7.
// A-frag: A[m=lane&15][k=(lane>>4)*8+j]  (m120-verified).

#define TT 512
#define HH 50
#define BT 16

typedef short short8 __attribute__((ext_vector_type(8)));
typedef float floatx4 __attribute__((ext_vector_type(4)));

static __device__ __forceinline__ float fast_sig(float x) {
    float e = __builtin_amdgcn_exp2f(x * -1.44269504f);   // exp(-x)
    return __builtin_amdgcn_rcpf(1.0f + e);
}
static __device__ __forceinline__ float fast_tanh(float x) {
    float e = __builtin_amdgcn_exp2f(x * -2.88539008f);   // exp(-2x)
    return __builtin_amdgcn_rcpf(1.0f + e) * 2.0f - 1.0f;
}
static __device__ __forceinline__ void split_bf16(float x, short& hi, short& lo) {
    unsigned u = __float_as_uint(x);
    hi = (short)(u >> 16);
    float xh = __uint_as_float(u & 0xffff0000u);
    lo = (short)(__float_as_uint(x - xh) >> 16);
}

__global__ __launch_bounds__(512, 2) void lstm_mfma(
    const float* __restrict__ x,
    const float* __restrict__ W_ih0, const float* __restrict__ W_hh0,
    const float* __restrict__ b_ih0, const float* __restrict__ b_hh0,
    const float* __restrict__ W_ih1, const float* __restrict__ W_hh1,
    const float* __restrict__ b_ih1, const float* __restrict__ b_hh1,
    const float* __restrict__ W_fc,  const float* __restrict__ b_fc,
    float* __restrict__ out)
{
    __shared__ __align__(16) short Hhi[2][4 * 64 * 8];   // [buf][ks][lane][j]
    __shared__ __align__(16) short Hlo[2][4 * 64 * 8];
    __shared__ float xs[TT * BT];
    __shared__ float h2f[BT * HH];

    const int tid = threadIdx.x;
    const int ln  = tid & 63;
    const int wv  = tid >> 6;
    const int m   = ln & 15;      // batch col (B n-index, A row-in-tile, C col)
    const int q   = ln >> 4;      // quad (A k-group, C row-group)
    const int b0g = blockIdx.x * BT;

    // ---------------- one-time init ----------------
    for (int i = tid; i < BT * TT; i += 512) {
        int b = i & 15, t = i >> 4;
        xs[t * BT + b] = x[(size_t)(b0g + b) * TT + t];
    }
    for (int i = tid; i < 2 * 4 * 64 * 8; i += 512) {
        ((short*)Hhi)[i] = 0; ((short*)Hlo)[i] = 0;
    }

    // ---- A-fragments (gate-interleaved rows), compile-time indexed ----
    // A-load: lane (q,m) of tile t supplies packed row pr = t*16 + m,
    //   i.e. unit uA = 4t + (m>>2), gate gA = m&3 -> W row = gA*50 + uA.
    // k within fragment = q*8 + j (+ 32*ks).
    short8 a0h[2][2], a0l[2][2];          // [slot][ks]  layer-0 (W_hh0)
    short8 a1h[2][4], a1l[2][4];          // [slot][ks]  layer-1 ([W_ih1|W_hh1])
    float  bb0[2][4], bw0[2][4], bb1[2][4];   // C-lane row constants per gate

#pragma unroll
    for (int slot = 0; slot < 2; ++slot) {
        const int tile = (slot == 0) ? wv : (8 + wv);
        const int uA   = 4 * tile + (m >> 2);
        const int gA   = m & 3;
        const bool rokA = (uA < HH);
        const int wrow = gA * HH + uA;    // row in original W layout
#pragma unroll
        for (int ks = 0; ks < 2; ++ks) {
            short8 h8, l8;
#pragma unroll
            for (int j = 0; j < 8; ++j) {
                int k = ks * 32 + q * 8 + j;
                float w = (rokA && k < HH) ? W_hh0[wrow * HH + k] : 0.f;
                short hi, lo; split_bf16(w, hi, lo);
                h8[j] = hi; l8[j] = lo;
            }
            a0h[slot][ks] = h8; a0l[slot][ks] = l8;
        }
#pragma unroll
        for (int ks = 0; ks < 4; ++ks) {
            short8 h8, l8;
#pragma unroll
            for (int j = 0; j < 8; ++j) {
                int k = ks * 32 + q * 8 + j;
                float w = 0.f;
                if (rokA) {
                    if (k < HH)                      w = W_ih1[wrow * HH + k];
                    else if (k >= 64 && k < 64 + HH) w = W_hh1[wrow * HH + (k - 64)];
                }
                short hi, lo; split_bf16(w, hi, lo);
                h8[j] = hi; l8[j] = lo;
            }
            a1h[slot][ks] = h8; a1l[slot][ks] = l8;
        }
        // C-lane constants: this lane's unit is uC = 4*tile + q; gate g = reg.
        const int uC = 4 * tile + q;
        const bool rokC = (uC < HH);
#pragma unroll
        for (int g = 0; g < 4; ++g) {
            int rg = g * HH + uC;
            bw0[slot][g] = rokC ? W_ih0[rg] : 0.f;
            bb0[slot][g] = rokC ? (b_ih0[rg] + b_hh0[rg]) : 0.f;
            bb1[slot][g] = rokC ? (b_ih1[rg] + b_hh1[rg]) : 0.f;
        }
    }

    // per-lane cell state + h-fragment write indices
    const int uC0 = 4 * wv + q;               // slot0 unit (0..31, always valid)
    const int uC1 = 32 + 4 * wv + q;          // slot1 unit (valid if wv<5 && <50)
    const bool v1 = (wv < 5) && (uC1 < HH);
    const int widx0 = ((uC0 >> 5) * 64 + ((uC0 >> 3) & 3) * 16 + m) * 8 + (uC0 & 7);
    const int widx1 = ((uC1 >> 5) * 64 + ((uC1 >> 3) & 3) * 16 + m) * 8 + (uC1 & 7);
    // h2 slot (k = 64+u) is exactly +1024 shorts from the h1 slot.
    float c1s0 = 0.f, c1s1 = 0.f, c2s0 = 0.f, c2s1 = 0.f;

    __syncthreads();

    // ---------------- time loop: ONE barrier per iteration ----------------
    for (int tt = 0; tt <= TT; ++tt) {
        const int p = tt & 1;

        // one Hcat snapshot read per wave (shared by both layers)
        short8 bh[4], bl[4];
#pragma unroll
        for (int ks = 0; ks < 4; ++ks) {
            bh[ks] = *(const short8*)&Hhi[p][(ks * 64 + ln) * 8];
            bl[ks] = *(const short8*)&Hlo[p][(ks * 64 + ln) * 8];
        }

        // ---- layer 0, t = tt: MFMA + in-register update -> h1(tt) ----
        if (tt < TT) {
            floatx4 acc[2];
            acc[0] = (floatx4){0.f, 0.f, 0.f, 0.f};
            acc[1] = (floatx4){0.f, 0.f, 0.f, 0.f};
#pragma unroll
            for (int ks = 0; ks < 2; ++ks) {
#pragma unroll
                for (int s = 0; s < 2; ++s) {
                    acc[s] = __builtin_amdgcn_mfma_f32_16x16x32_bf16(a0h[s][ks], bh[ks], acc[s], 0, 0, 0);
                    acc[s] = __builtin_amdgcn_mfma_f32_16x16x32_bf16(a0h[s][ks], bl[ks], acc[s], 0, 0, 0);
                    acc[s] = __builtin_amdgcn_mfma_f32_16x16x32_bf16(a0l[s][ks], bh[ks], acc[s], 0, 0, 0);
                }
            }
            const float xv = xs[tt * BT + m];
            // slot 0 (always valid)
            {
                float gi = acc[0][0] + bb0[0][0] + bw0[0][0] * xv;
                float gf = acc[0][1] + bb0[0][1] + bw0[0][1] * xv;
                float gg = acc[0][2] + bb0[0][2] + bw0[0][2] * xv;
                float go = acc[0][3] + bb0[0][3] + bw0[0][3] * xv;
                float c = fast_sig(gf) * c1s0 + fast_sig(gi) * fast_tanh(gg);
                c1s0 = c;
                float h = fast_sig(go) * fast_tanh(c);
                short hi, lo; split_bf16(h, hi, lo);
                Hhi[p ^ 1][widx0] = hi; Hlo[p ^ 1][widx0] = lo;
            }
            if (v1) {
                float gi = acc[1][0] + bb0[1][0] + bw0[1][0] * xv;
                float gf = acc[1][1] + bb0[1][1] + bw0[1][1] * xv;
                float gg = acc[1][2] + bb0[1][2] + bw0[1][2] * xv;
                float go = acc[1][3] + bb0[1][3] + bw0[1][3] * xv;
                float c = fast_sig(gf) * c1s1 + fast_sig(gi) * fast_tanh(gg);
                c1s1 = c;
                float h = fast_sig(go) * fast_tanh(c);
                short hi, lo; split_bf16(h, hi, lo);
                Hhi[p ^ 1][widx1] = hi; Hlo[p ^ 1][widx1] = lo;
            }
        }

        // ---- layer 1, t = tt-1: MFMA + in-register update -> h2(tt-1) ----
        if (tt > 0) {
            floatx4 acc[2];
            acc[0] = (floatx4){0.f, 0.f, 0.f, 0.f};
            acc[1] = (floatx4){0.f, 0.f, 0.f, 0.f};
#pragma unroll
            for (int ks = 0; ks < 4; ++ks) {
#pragma unroll
                for (int s = 0; s < 2; ++s) {
                    acc[s] = __builtin_amdgcn_mfma_f32_16x16x32_bf16(a1h[s][ks], bh[ks], acc[s], 0, 0, 0);
                    acc[s] = __builtin_amdgcn_mfma_f32_16x16x32_bf16(a1h[s][ks], bl[ks], acc[s], 0, 0, 0);
                    acc[s] = __builtin_amdgcn_mfma_f32_16x16x32_bf16(a1l[s][ks], bh[ks], acc[s], 0, 0, 0);
                }
            }
            // slot 0
            {
                float gi = acc[0][0] + bb1[0][0];
                float gf = acc[0][1] + bb1[0][1];
                float gg = acc[0][2] + bb1[0][2];
                float go = acc[0][3] + bb1[0][3];
                float c = fast_sig(gf) * c2s0 + fast_sig(gi) * fast_tanh(gg);
                c2s0 = c;
                float h = fast_sig(go) * fast_tanh(c);
                short hi, lo; split_bf16(h, hi, lo);
                Hhi[p ^ 1][widx0 + 1024] = hi; Hlo[p ^ 1][widx0 + 1024] = lo;
                if (tt == TT) h2f[m * HH + uC0] = h;
            }
            if (v1) {
                float gi = acc[1][0] + bb1[1][0];
                float gf = acc[1][1] + bb1[1][1];
                float gg = acc[1][2] + bb1[1][2];
                float go = acc[1][3] + bb1[1][3];
                float c = fast_sig(gf) * c2s1 + fast_sig(gi) * fast_tanh(gg);
                c2s1 = c;
                float h = fast_sig(go) * fast_tanh(c);
                short hi, lo; split_bf16(h, hi, lo);
                Hhi[p ^ 1][widx1 + 1024] = hi; Hlo[p ^ 1][widx1 + 1024] = lo;
                if (tt == TT) h2f[m * HH + uC1] = h;
            }
        }

        __syncthreads();   // writes to buf p^1 visible; next iter reads it
    }

    // ---------------- FC epilogue ----------------
    if (tid < BT) {
        float a = b_fc[0];
        for (int u = 0; u < HH; ++u)
            a = fmaf(h2f[tid * HH + u], W_fc[u], a);
        out[b0g + tid] = a;
    }
}

extern "C" void kernel_launch(void* const* d_in, const int* in_sizes, int n_in,
                              void* d_out, int out_size, void* d_ws, size_t ws_size,
                              hipStream_t stream) {
    const float* x     = (const float*)d_in[0];
    const float* W_ih0 = (const float*)d_in[1];
    const float* W_hh0 = (const float*)d_in[2];
    const float* b_ih0 = (const float*)d_in[3];
    const float* b_hh0 = (const float*)d_in[4];
    const float* W_ih1 = (const float*)d_in[5];
    const float* W_hh1 = (const float*)d_in[6];
    const float* b_ih1 = (const float*)d_in[7];
    const float* b_hh1 = (const float*)d_in[8];
    const float* W_fc  = (const float*)d_in[9];
    const float* b_fc  = (const float*)d_in[10];
    float* out = (float*)d_out;

    dim3 grid(4096 / BT);   // 256 blocks = 1/CU
    dim3 block(512);        // 8 waves
    lstm_mfma<<<grid, block, 0, stream>>>(x, W_ih0, W_hh0, b_ih0, b_hh0,
                                          W_ih1, W_hh1, b_ih1, b_hh1,
                                          W_fc, b_fc, out);
}